// Round 4
// baseline (66.760 us; speedup 1.0000x reference)
//
#include <hip/hip_runtime.h>

#define MAXLEN 768
#define DMODEL 512
#define ROWS_PER_WAVE 8
// conv output length T = MAXLEN - KSIZE + 1 = 766

typedef float f32x4 __attribute__((ext_vector_type(4)));

__global__ __launch_bounds__(256) void patch_embed_kernel(
    const float* __restrict__ x,
    const int*   __restrict__ lengths,
    const float* __restrict__ w,   // [DMODEL][3] row-major
    const float* __restrict__ b,   // [DMODEL]
    float*       __restrict__ out, // [N][DMODEL]
    int n_rows)
{
    const int lane = threadIdx.x & 63;
    const int wave = (int)((blockIdx.x * blockDim.x + threadIdx.x) >> 6);
    const int row0 = wave * ROWS_PER_WAVE;
    if (row0 >= n_rows) return;

    // --- hoist per-lane weights/bias once (loop-invariant): 32 VGPRs ---
    const int d0 = 4 * lane;           // outputs d0..d0+3
    const int d1 = 4 * lane + 256;     // outputs d1..d1+3
    const f32x4 wa0 = *reinterpret_cast<const f32x4*>(w + 3 * d0 + 0);
    const f32x4 wb0 = *reinterpret_cast<const f32x4*>(w + 3 * d0 + 4);
    const f32x4 wc0 = *reinterpret_cast<const f32x4*>(w + 3 * d0 + 8);
    const f32x4 bb0 = *reinterpret_cast<const f32x4*>(b + d0);
    const f32x4 wa1 = *reinterpret_cast<const f32x4*>(w + 3 * d1 + 0);
    const f32x4 wb1 = *reinterpret_cast<const f32x4*>(w + 3 * d1 + 4);
    const f32x4 wc1 = *reinterpret_cast<const f32x4*>(w + 3 * d1 + 8);
    const f32x4 bb1 = *reinterpret_cast<const f32x4*>(b + d1);

    // --- prologue: issue row0's loads ---
    const float* xr = x + (size_t)row0 * MAXLEN + 4 * lane;
    f32x4 va = __builtin_nontemporal_load(reinterpret_cast<const f32x4*>(xr));
    f32x4 vb = __builtin_nontemporal_load(reinterpret_cast<const f32x4*>(xr + 256));
    f32x4 vc = __builtin_nontemporal_load(reinterpret_cast<const f32x4*>(xr + 512));
    int L = lengths[row0];

    for (int i = 0; i < ROWS_PER_WAVE; ++i) {
        const int row = row0 + i;
        if (row >= n_rows) break;

        // --- prefetch row i+1 (stays in flight across this row's compute) ---
        f32x4 na = va, nb = vb, nc = vc;
        int nL = L;
        if (i + 1 < ROWS_PER_WAVE && row + 1 < n_rows) {
            const float* xn = x + (size_t)(row + 1) * MAXLEN + 4 * lane;
            na = __builtin_nontemporal_load(reinterpret_cast<const f32x4*>(xn));
            nb = __builtin_nontemporal_load(reinterpret_cast<const f32x4*>(xn + 256));
            nc = __builtin_nontemporal_load(reinterpret_cast<const f32x4*>(xn + 512));
            nL = lengths[row + 1];
        }

        // --- masked partial sums (3 independent chains) ---
        float e0 = 0.0f, e1 = 0.0f, e766 = 0.0f, e767 = 0.0f;
        float sa, sb, sc;
        {
            const int p = 4 * lane;
            const float v0 = (p + 0 < L) ? va.x : 0.0f;
            const float v1 = (p + 1 < L) ? va.y : 0.0f;
            const float v2 = (p + 2 < L) ? va.z : 0.0f;
            const float v3 = (p + 3 < L) ? va.w : 0.0f;
            sa = (v0 + v1) + (v2 + v3);
            if (lane == 0) { e0 = v0; e1 = v1; }
        }
        {
            const int p = 4 * lane + 256;
            const float v0 = (p + 0 < L) ? vb.x : 0.0f;
            const float v1 = (p + 1 < L) ? vb.y : 0.0f;
            const float v2 = (p + 2 < L) ? vb.z : 0.0f;
            const float v3 = (p + 3 < L) ? vb.w : 0.0f;
            sb = (v0 + v1) + (v2 + v3);
        }
        {
            const int p = 4 * lane + 512;
            const float v0 = (p + 0 < L) ? vc.x : 0.0f;
            const float v1 = (p + 1 < L) ? vc.y : 0.0f;
            const float v2 = (p + 2 < L) ? vc.z : 0.0f;
            const float v3 = (p + 3 < L) ? vc.w : 0.0f;
            sc = (v0 + v1) + (v2 + v3);
            if (lane == 63) { e766 = v2; e767 = v3; }
        }
        float s = (sa + sb) + sc;

        // wave-64 tree reduction + edge broadcasts
#pragma unroll
        for (int off = 32; off > 0; off >>= 1)
            s += __shfl_xor(s, off, 64);
        e0   = __shfl(e0, 0, 64);
        e1   = __shfl(e1, 0, 64);
        e766 = __shfl(e766, 63, 64);
        e767 = __shfl(e767, 63, 64);

        const float inv = 1.0f / 766.0f;
        const float m0 = (s - e766 - e767) * inv;
        const float m1 = (s - e0 - e767) * inv;
        const float m2 = (s - e0 - e1) * inv;

        // --- epilogue: out[row, d] = b[d] + m0*w[d,0] + m1*w[d,1] + m2*w[d,2] ---
        float* orow = out + (size_t)row * DMODEL;
        f32x4 o0, o1;
        o0.x = bb0.x + m0 * wa0.x + m1 * wa0.y + m2 * wa0.z;
        o0.y = bb0.y + m0 * wa0.w + m1 * wb0.x + m2 * wb0.y;
        o0.z = bb0.z + m0 * wb0.z + m1 * wb0.w + m2 * wc0.x;
        o0.w = bb0.w + m0 * wc0.y + m1 * wc0.z + m2 * wc0.w;
        o1.x = bb1.x + m0 * wa1.x + m1 * wa1.y + m2 * wa1.z;
        o1.y = bb1.y + m0 * wa1.w + m1 * wb1.x + m2 * wb1.y;
        o1.z = bb1.z + m0 * wb1.z + m1 * wb1.w + m2 * wc1.x;
        o1.w = bb1.w + m0 * wc1.y + m1 * wc1.z + m2 * wc1.w;
        __builtin_nontemporal_store(o0, reinterpret_cast<f32x4*>(orow + d0));
        __builtin_nontemporal_store(o1, reinterpret_cast<f32x4*>(orow + d1));

        va = na; vb = nb; vc = nc; L = nL;
    }
}

extern "C" void kernel_launch(void* const* d_in, const int* in_sizes, int n_in,
                              void* d_out, int out_size, void* d_ws, size_t ws_size,
                              hipStream_t stream) {
    const float* x       = (const float*)d_in[0];
    const int*   lengths = (const int*)  d_in[1];
    const float* conv_w  = (const float*)d_in[2];
    const float* conv_b  = (const float*)d_in[3];
    float* out = (float*)d_out;

    const int n_rows = in_sizes[1];                       // 65536
    const int rows_per_block = 4 * ROWS_PER_WAVE;         // 4 waves/block
    const int grid = (n_rows + rows_per_block - 1) / rows_per_block;  // 2048

    patch_embed_kernel<<<grid, 256, 0, stream>>>(x, lengths, conv_w, conv_b, out, n_rows);
}

// Round 5
// 55.187 us; speedup vs baseline: 1.2097x; 1.2097x over previous
//
#include <hip/hip_runtime.h>

#define MAXLEN 768
#define DMODEL 512
// conv output length T = MAXLEN - KSIZE + 1 = 766

typedef float f32x4 __attribute__((ext_vector_type(4)));

// Kernel 1: pure read stream. One wave per row: masked sum + edges -> (m0,m1,m2).
__global__ __launch_bounds__(256) void rowsum_kernel(
    const float* __restrict__ x,
    const int*   __restrict__ lengths,
    f32x4*       __restrict__ sums,   // [N] {m0,m1,m2,0}
    int n_rows)
{
    const int lane = threadIdx.x & 63;
    const int row  = (int)((blockIdx.x * blockDim.x + threadIdx.x) >> 6);
    if (row >= n_rows) return;

    const float* xr = x + (size_t)row * MAXLEN + 4 * lane;
    const f32x4 va = __builtin_nontemporal_load(reinterpret_cast<const f32x4*>(xr));
    const f32x4 vb = __builtin_nontemporal_load(reinterpret_cast<const f32x4*>(xr + 256));
    const f32x4 vc = __builtin_nontemporal_load(reinterpret_cast<const f32x4*>(xr + 512));
    const int L = lengths[row];

    float e0 = 0.0f, e1 = 0.0f, e766 = 0.0f, e767 = 0.0f;
    float sa, sb, sc;
    {
        const int p = 4 * lane;
        const float v0 = (p + 0 < L) ? va.x : 0.0f;
        const float v1 = (p + 1 < L) ? va.y : 0.0f;
        const float v2 = (p + 2 < L) ? va.z : 0.0f;
        const float v3 = (p + 3 < L) ? va.w : 0.0f;
        sa = (v0 + v1) + (v2 + v3);
        e0 = v0; e1 = v1;                       // valid on lane 0
    }
    {
        const int p = 4 * lane + 256;
        const float v0 = (p + 0 < L) ? vb.x : 0.0f;
        const float v1 = (p + 1 < L) ? vb.y : 0.0f;
        const float v2 = (p + 2 < L) ? vb.z : 0.0f;
        const float v3 = (p + 3 < L) ? vb.w : 0.0f;
        sb = (v0 + v1) + (v2 + v3);
    }
    {
        const int p = 4 * lane + 512;
        const float v0 = (p + 0 < L) ? vc.x : 0.0f;
        const float v1 = (p + 1 < L) ? vc.y : 0.0f;
        const float v2 = (p + 2 < L) ? vc.z : 0.0f;
        const float v3 = (p + 3 < L) ? vc.w : 0.0f;
        sc = (v0 + v1) + (v2 + v3);
        e766 = v2; e767 = v3;                   // valid on lane 63
    }
    float s = (sa + sb) + sc;

#pragma unroll
    for (int off = 32; off > 0; off >>= 1)
        s += __shfl_xor(s, off, 64);
    e766 = __shfl(e766, 63, 64);
    e767 = __shfl(e767, 63, 64);

    if (lane == 0) {
        const float inv = 1.0f / 766.0f;
        f32x4 m;
        m.x = (s - e766 - e767) * inv;
        m.y = (s - e0 - e767) * inv;
        m.z = (s - e0 - e1) * inv;
        m.w = 0.0f;
        sums[row] = m;                          // normal store -> stays in L2/L3
    }
}

// Kernel 2: pure write stream. One wave per row: out[row,:] = b + m @ w^T.
__global__ __launch_bounds__(256) void expand_kernel(
    const f32x4* __restrict__ sums,
    const float* __restrict__ w,   // [DMODEL][3] row-major
    const float* __restrict__ b,   // [DMODEL]
    float*       __restrict__ out, // [N][DMODEL]
    int n_rows)
{
    const int lane = threadIdx.x & 63;
    const int row  = (int)((blockIdx.x * blockDim.x + threadIdx.x) >> 6);
    if (row >= n_rows) return;

    const f32x4 m = sums[row];                  // L3-hot broadcast load
    const float m0 = m.x, m1 = m.y, m2 = m.z;

    float* orow = out + (size_t)row * DMODEL;
#pragma unroll
    for (int j = 0; j < 2; ++j) {
        const int d = 4 * lane + 256 * j;
        const f32x4 wa = *reinterpret_cast<const f32x4*>(w + 3 * d + 0);
        const f32x4 wb = *reinterpret_cast<const f32x4*>(w + 3 * d + 4);
        const f32x4 wc = *reinterpret_cast<const f32x4*>(w + 3 * d + 8);
        const f32x4 bb = *reinterpret_cast<const f32x4*>(b + d);
        f32x4 o;
        o.x = bb.x + m0 * wa.x + m1 * wa.y + m2 * wa.z;
        o.y = bb.y + m0 * wa.w + m1 * wb.x + m2 * wb.y;
        o.z = bb.z + m0 * wb.z + m1 * wb.w + m2 * wc.x;
        o.w = bb.w + m0 * wc.y + m1 * wc.z + m2 * wc.w;
        __builtin_nontemporal_store(o, reinterpret_cast<f32x4*>(orow + d));
    }
}

extern "C" void kernel_launch(void* const* d_in, const int* in_sizes, int n_in,
                              void* d_out, int out_size, void* d_ws, size_t ws_size,
                              hipStream_t stream) {
    const float* x       = (const float*)d_in[0];
    const int*   lengths = (const int*)  d_in[1];
    const float* conv_w  = (const float*)d_in[2];
    const float* conv_b  = (const float*)d_in[3];
    float* out = (float*)d_out;
    f32x4* sums = (f32x4*)d_ws;                   // 65536 * 16 B = 1 MB scratch

    const int n_rows = in_sizes[1];               // 65536
    const int grid = (n_rows + 3) / 4;            // 4 waves/block, 1 row/wave

    rowsum_kernel<<<grid, 256, 0, stream>>>(x, lengths, sums, n_rows);
    expand_kernel<<<grid, 256, 0, stream>>>(sums, conv_w, conv_b, out, n_rows);
}

// Round 6
// 49.902 us; speedup vs baseline: 1.3378x; 1.1059x over previous
//
#include <hip/hip_runtime.h>

#define MAXLEN 768
#define DMODEL 512
// conv output length T = MAXLEN - KSIZE + 1 = 766

typedef float f32x4 __attribute__((ext_vector_type(4)));

// Kernel 1: pure read stream. One wave per row: masked sum + edges -> (m0,m1,m2).
// Lanes whose entire float4 lies beyond lengths[row] skip the load (no HBM fetch).
__global__ __launch_bounds__(256) void rowsum_kernel(
    const float* __restrict__ x,
    const int*   __restrict__ lengths,
    f32x4*       __restrict__ sums,   // [N] {m0,m1,m2,0}
    int n_rows)
{
    const int lane = threadIdx.x & 63;
    const int row  = (int)((blockIdx.x * blockDim.x + threadIdx.x) >> 6);
    if (row >= n_rows) return;

    const int L = lengths[row];
    const float* xr = x + (size_t)row * MAXLEN + 4 * lane;

    f32x4 va = {0.f, 0.f, 0.f, 0.f};
    f32x4 vb = {0.f, 0.f, 0.f, 0.f};
    f32x4 vc = {0.f, 0.f, 0.f, 0.f};
    // predicated loads: only fetch vectors that intersect the valid prefix
    if (4 * lane < L)
        va = __builtin_nontemporal_load(reinterpret_cast<const f32x4*>(xr));
    if (4 * lane + 256 < L)
        vb = __builtin_nontemporal_load(reinterpret_cast<const f32x4*>(xr + 256));
    if (4 * lane + 512 < L)
        vc = __builtin_nontemporal_load(reinterpret_cast<const f32x4*>(xr + 512));

    float e0 = 0.0f, e1 = 0.0f, e766 = 0.0f, e767 = 0.0f;
    float sa, sb, sc;
    {
        const int p = 4 * lane;
        const float v0 = (p + 0 < L) ? va.x : 0.0f;
        const float v1 = (p + 1 < L) ? va.y : 0.0f;
        const float v2 = (p + 2 < L) ? va.z : 0.0f;
        const float v3 = (p + 3 < L) ? va.w : 0.0f;
        sa = (v0 + v1) + (v2 + v3);
        e0 = v0; e1 = v1;                       // valid on lane 0 (L >= 3 always)
    }
    {
        const int p = 4 * lane + 256;
        const float v0 = (p + 0 < L) ? vb.x : 0.0f;
        const float v1 = (p + 1 < L) ? vb.y : 0.0f;
        const float v2 = (p + 2 < L) ? vb.z : 0.0f;
        const float v3 = (p + 3 < L) ? vb.w : 0.0f;
        sb = (v0 + v1) + (v2 + v3);
    }
    {
        const int p = 4 * lane + 512;
        const float v0 = (p + 0 < L) ? vc.x : 0.0f;
        const float v1 = (p + 1 < L) ? vc.y : 0.0f;
        const float v2 = (p + 2 < L) ? vc.z : 0.0f;
        const float v3 = (p + 3 < L) ? vc.w : 0.0f;
        sc = (v0 + v1) + (v2 + v3);
        e766 = v2; e767 = v3;                   // valid on lane 63 (0 if L<=766: masked)
    }
    float s = (sa + sb) + sc;

#pragma unroll
    for (int off = 32; off > 0; off >>= 1)
        s += __shfl_xor(s, off, 64);
    e766 = __shfl(e766, 63, 64);
    e767 = __shfl(e767, 63, 64);

    if (lane == 0) {
        const float inv = 1.0f / 766.0f;
        f32x4 m;
        m.x = (s - e766 - e767) * inv;
        m.y = (s - e0 - e767) * inv;
        m.z = (s - e0 - e1) * inv;
        m.w = 0.0f;
        sums[row] = m;                          // normal store -> stays in L2/L3
    }
}

// Kernel 2: pure write stream. One wave per row: out[row,:] = b + m @ w^T.
__global__ __launch_bounds__(256) void expand_kernel(
    const f32x4* __restrict__ sums,
    const float* __restrict__ w,   // [DMODEL][3] row-major
    const float* __restrict__ b,   // [DMODEL]
    float*       __restrict__ out, // [N][DMODEL]
    int n_rows)
{
    const int lane = threadIdx.x & 63;
    const int row  = (int)((blockIdx.x * blockDim.x + threadIdx.x) >> 6);
    if (row >= n_rows) return;

    const f32x4 m = sums[row];                  // L2/L3-hot load
    const float m0 = m.x, m1 = m.y, m2 = m.z;

    float* orow = out + (size_t)row * DMODEL;
#pragma unroll
    for (int j = 0; j < 2; ++j) {
        const int d = 4 * lane + 256 * j;
        const f32x4 wa = *reinterpret_cast<const f32x4*>(w + 3 * d + 0);
        const f32x4 wb = *reinterpret_cast<const f32x4*>(w + 3 * d + 4);
        const f32x4 wc = *reinterpret_cast<const f32x4*>(w + 3 * d + 8);
        const f32x4 bb = *reinterpret_cast<const f32x4*>(b + d);
        f32x4 o;
        o.x = bb.x + m0 * wa.x + m1 * wa.y + m2 * wa.z;
        o.y = bb.y + m0 * wa.w + m1 * wb.x + m2 * wb.y;
        o.z = bb.z + m0 * wb.z + m1 * wb.w + m2 * wc.x;
        o.w = bb.w + m0 * wc.y + m1 * wc.z + m2 * wc.w;
        __builtin_nontemporal_store(o, reinterpret_cast<f32x4*>(orow + d));
    }
}

extern "C" void kernel_launch(void* const* d_in, const int* in_sizes, int n_in,
                              void* d_out, int out_size, void* d_ws, size_t ws_size,
                              hipStream_t stream) {
    const float* x       = (const float*)d_in[0];
    const int*   lengths = (const int*)  d_in[1];
    const float* conv_w  = (const float*)d_in[2];
    const float* conv_b  = (const float*)d_in[3];
    float* out = (float*)d_out;
    f32x4* sums = (f32x4*)d_ws;                   // 65536 * 16 B = 1 MB scratch

    const int n_rows = in_sizes[1];               // 65536
    const int grid = (n_rows + 3) / 4;            // 4 waves/block, 1 row/wave

    rowsum_kernel<<<grid, 256, 0, stream>>>(x, lengths, sums, n_rows);
    expand_kernel<<<grid, 256, 0, stream>>>(sums, conv_w, conv_b, out, n_rows);
}